// Round 1
// 411.317 us; speedup vs baseline: 1.0260x; 1.0260x over previous
//
#include <hip/hip_runtime.h>

// Problem constants (match reference)
#define N_L   90
#define N_B   20
#define N_MU  46
#define N_LF  51
#define N_CELLS (N_L * N_B * N_MU)      // 82800
#define N_OUTK  (N_LF - N_MU + 1)       // 6
#define N_PART  20000000
#define QUADS   (N_PART / 4)            // 5,000,000
#define HIST_BLOCK 1024

// ---------------- single-pass u16-packed config (main path) ----------------
// Full 82800-cell grid as u16 pairs packed into u32 words: 41400 words.
// 40960 words (= 160 KiB) live in LDS; last 440 words (880 cells, 1.06%)
// spill to global u32 atomics. Mass fixed-point scale 2^12: per-block cell
// sums are Poisson lambda~1 (C>=128), so low-half sums stay far below 16.0
// mass units (carry boundary 65536); a carry would only leak 1 ulp
// (2.4e-4) into the neighbor cell. Reduction is exact u32 after unpack.
#define LDS_WORDS 40960
#define TOT_WORDS (N_L * N_B * (N_MU / 2))     // 41400
#define SPILLW    (TOT_WORDS - LDS_WORDS)      // 440 words -> 880 u32 cells
#define N_CELLS16 (2 * LDS_WORDS)              // 81920 cells resident in LDS
#define MSC1      4096.0f
#define MSC1_INV  (1.0f / 4096.0f)
#define C1_MAX    256
#define RP1       8                            // reduce parallelism over C
#define K_UNROLL  8

// 4-byte-aligned float4: one overlapping 16B load per particle (stride 12B
// per lane -> contiguous, ~2x fewer L1 line transactions than 48B-stride).
typedef float f4a4 __attribute__((ext_vector_type(4), aligned(4)));

// ---- R=2 fallback config (u32 fixed-point, previous round's design)
#define L_PER2      45
#define RANGE_CELLS (L_PER2 * N_B * N_MU)      // 41400
#define LDS_CELLS   40960                      // 160 KiB exactly
#define SPILL_PER   (RANGE_CELLS - LDS_CELLS)  // 440
#define C2_MAX      128
#define VEC2        (LDS_CELLS / 4)            // 10240 uint4 per range
#define RPARTS      4
#define MSCALE      8388608.0f
#define MSCALE_INV  (1.0f / 8388608.0f)

// ---- R=3 fallback config (f32)
#define L_PER3  30
#define SLICE3  (L_PER3 * N_B * N_MU)          // 27600 floats
#define C3_MAX  85

// ---------------- binning math --------------------------------------------
// Reference: idx = round((x - min)/dx), dx = f32((maxs-mins)/(ns-1)).
// rintf(fmaf(x, 1/dx, -min/dx)): biases 44.5 / 9.5 / -35 are EXACT.
__device__ __forceinline__ void compute_idx(float x, float y, float z,
                                            int& i0, int& i1, int& i2) {
    i0 = (int)rintf(fmaf(x, 89.0f / 180.0f, 44.5f));
    i1 = (int)rintf(fmaf(y, 19.0f / 24.0f,  9.5f));
    i2 = (int)rintf(fmaf(z, 5.0f,          -35.0f));
}

// ---------------- single-pass u16 main path --------------------------------

__device__ __forceinline__ void bin1(bool v, float x, float y, float z, float m,
                                     unsigned* __restrict__ s_hist,
                                     unsigned* __restrict__ spill) {
    int i0, i1, i2;
    compute_idx(x, y, z, i0, i1, i2);
    bool ok = v & ((unsigned)i0 < N_L) & ((unsigned)i1 < N_B) &
              ((unsigned)i2 < N_MU);
    if (ok) {
        unsigned mq = (unsigned)(int)rintf(m * MSC1);        // 12-bit fixed pt
        int w = (i0 * N_B + i1) * (N_MU / 2) + (i2 >> 1);    // packed word
        unsigned val = mq << ((i2 & 1) << 4);                // lo/hi halfword
        if (w < LDS_WORDS) atomicAdd(&s_hist[w], val);       // ds_add_u32
        else atomicAdd(&spill[((w - LDS_WORDS) << 1) + (i2 & 1)], mq);
    }
}

__global__ __launch_bounds__(HIST_BLOCK) void hist1_kernel(
        const float* __restrict__ lbm,       // [N_PART*3] f32
        const float* __restrict__ mass,      // [N_PART]   f32
        unsigned* __restrict__ slices,       // [C][LDS_WORDS]
        unsigned* __restrict__ spill,        // [2*SPILLW], pre-zeroed
        int C, int ppc) {
    __shared__ unsigned s_hist[LDS_WORDS];
    uint4* sh4 = (uint4*)s_hist;
    #pragma unroll
    for (int i = threadIdx.x; i < LDS_WORDS / 4; i += HIST_BLOCK)
        sh4[i] = make_uint4(0u, 0u, 0u, 0u);
    __syncthreads();

    int c  = blockIdx.x;
    int p0 = c * ppc;
    int p1 = p0 + ppc;
    // Exclude the global last particle: its overlapping 16B load would read
    // 4B past the array. It is handled scalar by block 0, thread 0 below.
    if (p1 > N_PART - 1) p1 = N_PART - 1;

    for (int p = p0 + (int)threadIdx.x; p < p1; p += K_UNROLL * HIST_BLOCK) {
        f4a4  vv[K_UNROLL];
        float mm[K_UNROLL];
        bool  vl[K_UNROLL];
        #pragma unroll
        for (int k = 0; k < K_UNROLL; ++k) {
            int pk = p + k * HIST_BLOCK;
            bool v = pk < p1;
            int pl = v ? pk : p;                         // clamped, in-bounds
            vv[k] = *(const f4a4*)(lbm + 3 * (size_t)pl);   // 16B @ align4
            mm[k] = mass[pl];
            vl[k] = v;
        }
        #pragma unroll
        for (int k = 0; k < K_UNROLL; ++k)
            bin1(vl[k], vv[k].x, vv[k].y, vv[k].z, mm[k], s_hist, spill);
    }

    if (blockIdx.x == 0 && threadIdx.x == 0) {
        size_t p = N_PART - 1;                           // the excluded one
        bin1(true, lbm[3 * p], lbm[3 * p + 1], lbm[3 * p + 2], mass[p],
             s_hist, spill);
    }
    __syncthreads();

    // flush: plain coalesced 16B stores, zero atomics
    uint4* dst = (uint4*)(slices + (size_t)c * LDS_WORDS);
    #pragma unroll
    for (int i = threadIdx.x; i < LDS_WORDS / 4; i += HIST_BLOCK)
        dst[i] = sh4[i];
}

// reduce pass A: 8-way parallel over C; unpack u16 halves, exact u32 sums.
// partial layout: uint4 partial4[RP1][LDS_WORDS/4][2]  (8 u32 cells / word4)
__global__ __launch_bounds__(256) void reduce1a_kernel(
        const unsigned* __restrict__ slices,
        unsigned* __restrict__ partial, int C) {
    int t = blockIdx.x * 256 + threadIdx.x;
    if (t >= RP1 * (LDS_WORDS / 4)) return;
    int pr = t / (LDS_WORDS / 4);
    int i4 = t - pr * (LDS_WORDS / 4);
    int clo = (pr * C) / RP1, chi = ((pr + 1) * C) / RP1;
    const uint4* p = (const uint4*)slices + i4;
    unsigned a0 = 0, a1 = 0, a2 = 0, a3 = 0, a4 = 0, a5 = 0, a6 = 0, a7 = 0;
    for (int cc = clo; cc < chi; ++cc) {
        uint4 v = p[(size_t)cc * (LDS_WORDS / 4)];
        a0 += v.x & 0xFFFFu; a1 += v.x >> 16;
        a2 += v.y & 0xFFFFu; a3 += v.y >> 16;
        a4 += v.z & 0xFFFFu; a5 += v.z >> 16;
        a6 += v.w & 0xFFFFu; a7 += v.w >> 16;
    }
    uint4* dst = ((uint4*)partial) + (size_t)t * 2;
    dst[0] = make_uint4(a0, a1, a2, a3);
    dst[1] = make_uint4(a4, a5, a6, a7);
}

// reduce pass B: combine 8 partials + spill, convert to f32 hist (natural
// (l,b,mu) order -- packed word order IS the natural cell order).
__global__ __launch_bounds__(256) void reduce1b_kernel(
        const unsigned* __restrict__ partial,
        const unsigned* __restrict__ spill,
        float* __restrict__ hist) {
    int t = blockIdx.x * 256 + threadIdx.x;      // cell-quad index
    if (t < N_CELLS16 / 4) {
        const uint4* base = (const uint4*)partial + t;
        unsigned sx = 0, sy = 0, sz = 0, sw = 0;
        #pragma unroll
        for (int pr = 0; pr < RP1; ++pr) {
            uint4 v = base[(size_t)pr * (LDS_WORDS / 2)];  // (LDS_WORDS/4)*2
            sx += v.x; sy += v.y; sz += v.z; sw += v.w;
        }
        float4 f;
        f.x = (float)sx * MSC1_INV;
        f.y = (float)sy * MSC1_INV;
        f.z = (float)sz * MSC1_INV;
        f.w = (float)sw * MSC1_INV;
        ((float4*)hist)[t] = f;
    } else {
        int u = t - N_CELLS16 / 4;
        if (u < 2 * SPILLW)
            hist[N_CELLS16 + u] = (float)spill[u] * MSC1_INV;
    }
}

// ---------------- R=2 fallback path (u32, previous round) ------------------

__device__ __forceinline__ void bin2u(bool v, float x, float y, float z, float m,
                                      int l_lo, unsigned* __restrict__ s_hist,
                                      unsigned* __restrict__ spill_r) {
    int i0, i1, i2;
    compute_idx(x, y, z, i0, i1, i2);
    int il = i0 - l_lo;
    bool ok = v & ((unsigned)il < L_PER2) & ((unsigned)i1 < N_B) &
              ((unsigned)i2 < N_MU);
    if (ok) {
        unsigned mu = (unsigned)(int)rintf(m * MSCALE);
        int f = (il * N_B + i1) * N_MU + i2;
        if (f < LDS_CELLS) atomicAdd(&s_hist[f], mu);
        else atomicAdd(&spill_r[f - LDS_CELLS], mu);
    }
}

__global__ __launch_bounds__(HIST_BLOCK) void hist2_kernel(
        const float4* __restrict__ lbm4,
        const float4* __restrict__ m4,
        unsigned* __restrict__ slices,
        unsigned* __restrict__ spill,
        int C, int qpc) {
    __shared__ unsigned s_hist[LDS_CELLS];
    int bid = blockIdx.x;
    int r   = (bid >> 3) & 1;
    int c   = ((bid >> 4) << 3) + (bid & 7);
    int l_lo = r * L_PER2;
    unsigned* spill_r = spill + r * SPILL_PER;

    uint4* sh4 = (uint4*)s_hist;
    #pragma unroll
    for (int i = threadIdx.x; i < LDS_CELLS / 4; i += HIST_BLOCK)
        sh4[i] = make_uint4(0u, 0u, 0u, 0u);
    __syncthreads();

    int q0 = c * qpc;
    int q1 = q0 + qpc;
    if (q1 > QUADS) q1 = QUADS;
    const int S = HIST_BLOCK;
    for (int q = q0 + (int)threadIdx.x; q < q1; q += 2 * S) {
        int p  = q + S;
        bool vp = p < q1;
        int pl = vp ? p : q;
        float4 a0 = lbm4[3 * q + 0];
        float4 b0 = lbm4[3 * q + 1];
        float4 c0 = lbm4[3 * q + 2];
        float4 a1 = lbm4[3 * pl + 0];
        float4 b1 = lbm4[3 * pl + 1];
        float4 c1 = lbm4[3 * pl + 2];
        float4 m0 = m4[q];
        float4 m1 = m4[pl];
        bin2u(true, a0.x, a0.y, a0.z, m0.x, l_lo, s_hist, spill_r);
        bin2u(true, a0.w, b0.x, b0.y, m0.y, l_lo, s_hist, spill_r);
        bin2u(true, b0.z, b0.w, c0.x, m0.z, l_lo, s_hist, spill_r);
        bin2u(true, c0.y, c0.z, c0.w, m0.w, l_lo, s_hist, spill_r);
        bin2u(vp, a1.x, a1.y, a1.z, m1.x, l_lo, s_hist, spill_r);
        bin2u(vp, a1.w, b1.x, b1.y, m1.y, l_lo, s_hist, spill_r);
        bin2u(vp, b1.z, b1.w, c1.x, m1.z, l_lo, s_hist, spill_r);
        bin2u(vp, c1.y, c1.z, c1.w, m1.w, l_lo, s_hist, spill_r);
    }
    __syncthreads();

    uint4* dst = (uint4*)(slices + (size_t)(r * C + c) * LDS_CELLS);
    #pragma unroll
    for (int i = threadIdx.x; i < LDS_CELLS / 4; i += HIST_BLOCK)
        dst[i] = sh4[i];
}

__global__ __launch_bounds__(256) void reduce2a_kernel(
        const unsigned* __restrict__ slices,
        unsigned* __restrict__ partial,
        int C) {
    int t = blockIdx.x * 256 + threadIdx.x;
    if (t >= RPARTS * 2 * VEC2) return;
    int pr = t / (2 * VEC2);
    int j  = t - pr * 2 * VEC2;
    int r  = j / VEC2;
    int f4 = j - r * VEC2;
    int clo = (pr * C) / RPARTS, chi = ((pr + 1) * C) / RPARTS;
    const uint4* p = (const uint4*)(slices + (size_t)r * C * LDS_CELLS) + f4;
    uint4 s = make_uint4(0u, 0u, 0u, 0u);
    for (int cc = clo; cc < chi; ++cc) {
        uint4 v = p[(size_t)cc * VEC2];
        s.x += v.x; s.y += v.y; s.z += v.z; s.w += v.w;
    }
    ((uint4*)partial)[(size_t)pr * 2 * VEC2 + j] = s;
}

__global__ __launch_bounds__(256) void reduce2b_kernel(
        const unsigned* __restrict__ partial,
        const unsigned* __restrict__ spill,
        float* __restrict__ hist) {
    int t = blockIdx.x * 256 + threadIdx.x;
    if (t < 2 * VEC2) {
        int r  = t / VEC2;
        int f4 = t - r * VEC2;
        const uint4* p = (const uint4*)partial + t;
        uint4 s = make_uint4(0u, 0u, 0u, 0u);
        #pragma unroll
        for (int pr = 0; pr < RPARTS; ++pr) {
            uint4 v = p[(size_t)pr * 2 * VEC2];
            s.x += v.x; s.y += v.y; s.z += v.z; s.w += v.w;
        }
        float4 f;
        f.x = (float)s.x * MSCALE_INV;
        f.y = (float)s.y * MSCALE_INV;
        f.z = (float)s.z * MSCALE_INV;
        f.w = (float)s.w * MSCALE_INV;
        ((float4*)(hist + (size_t)r * RANGE_CELLS))[f4] = f;
    } else {
        int u = t - 2 * VEC2;
        if (u < 2 * SPILL_PER) {
            int r = u / SPILL_PER, sdx = u - r * SPILL_PER;
            hist[r * RANGE_CELLS + LDS_CELLS + sdx] =
                (float)spill[r * SPILL_PER + sdx] * MSCALE_INV;
        }
    }
}

// ---------------- R=3 fallback path (f32) ----------------------------------

__device__ __forceinline__ void bin3(float x, float y, float z, float m,
                                     int l_lo, float* __restrict__ s_hist) {
    int i0, i1, i2;
    compute_idx(x, y, z, i0, i1, i2);
    int il = i0 - l_lo;
    if (((unsigned)il < L_PER3) & ((unsigned)i1 < N_B) & ((unsigned)i2 < N_MU))
        atomicAdd(&s_hist[(il * N_B + i1) * N_MU + i2], m);
}

__global__ __launch_bounds__(HIST_BLOCK) void hist3_kernel(
        const float4* __restrict__ lbm4,
        const float4* __restrict__ m4,
        float* __restrict__ slices, int C, int qpc) {
    __shared__ float s_hist[SLICE3];
    int c = blockIdx.x / 3;
    int r = blockIdx.x % 3;
    int l_lo = r * L_PER3;
    for (int i = threadIdx.x; i < SLICE3; i += HIST_BLOCK) s_hist[i] = 0.0f;
    __syncthreads();
    int q0 = c * qpc, q1 = q0 + qpc;
    if (q1 > QUADS) q1 = QUADS;
    for (int q = q0 + threadIdx.x; q < q1; q += HIST_BLOCK) {
        float4 a = lbm4[3 * q + 0];
        float4 b = lbm4[3 * q + 1];
        float4 d = lbm4[3 * q + 2];
        float4 m = m4[q];
        bin3(a.x, a.y, a.z, m.x, l_lo, s_hist);
        bin3(a.w, b.x, b.y, m.y, l_lo, s_hist);
        bin3(b.z, b.w, d.x, m.z, l_lo, s_hist);
        bin3(d.y, d.z, d.w, m.w, l_lo, s_hist);
    }
    __syncthreads();
    float* dst = slices + (size_t)(r * C + c) * SLICE3;
    for (int i = threadIdx.x; i < SLICE3; i += HIST_BLOCK) dst[i] = s_hist[i];
}

__global__ __launch_bounds__(256) void reduce3_kernel(
        const float* __restrict__ slices, float* __restrict__ hist, int C) {
    int j = blockIdx.x * 256 + threadIdx.x;
    if (j >= N_CELLS) return;
    int r = j / SLICE3;
    int off = j - r * SLICE3;
    const float* p = slices + (size_t)(r * C) * SLICE3 + off;
    float s = 0.0f;
    for (int c = 0; c < C; ++c) s += p[(size_t)c * SLICE3];
    hist[j] = s;
}

// ---------------- tiny-ws fallback: global f32 atomics ----------------------

__global__ void zero_hist_kernel(float* __restrict__ hist) {
    int i = blockIdx.x * blockDim.x + threadIdx.x;
    if (i < N_CELLS) hist[i] = 0.0f;
}

__global__ __launch_bounds__(256) void hist_atomic_kernel(
        const float4* __restrict__ lbm4,
        const float4* __restrict__ m4,
        float* __restrict__ hist) {
    int q = blockIdx.x * blockDim.x + threadIdx.x;
    if (q >= QUADS) return;
    float4 a = lbm4[3 * q + 0];
    float4 b = lbm4[3 * q + 1];
    float4 d = lbm4[3 * q + 2];
    float4 m = m4[q];
    float xs[4] = {a.x, a.w, b.z, d.y};
    float ys[4] = {a.y, b.x, b.w, d.z};
    float zs[4] = {a.z, b.y, d.x, d.w};
    float ms[4] = {m.x, m.y, m.z, m.w};
    #pragma unroll
    for (int k = 0; k < 4; ++k) {
        int i0, i1, i2;
        compute_idx(xs[k], ys[k], zs[k], i0, i1, i2);
        if (((unsigned)i0 < N_L) & ((unsigned)i1 < N_B) & ((unsigned)i2 < N_MU))
            unsafeAtomicAdd(&hist[(i0 * N_B + i1) * N_MU + i2], ms[k]);
    }
}

// ---------------- conv epilogue ---------------------------------------------

__global__ __launch_bounds__(256) void conv_kernel(
        const float* __restrict__ hist,
        const float* __restrict__ lf,
        float* __restrict__ out) {
    __shared__ float s_lf[N_LF];
    int t = threadIdx.x;
    if (t < N_LF) s_lf[t] = lf[t];
    __syncthreads();
    int cell = blockIdx.x * blockDim.x + t;          // (l,b) pair, 1800 total
    if (cell < N_L * N_B) {
        float acc[N_OUTK];
        #pragma unroll
        for (int k = 0; k < N_OUTK; ++k) acc[k] = 0.0f;
        #pragma unroll 2
        for (int i = 0; i < N_MU; ++i) {
            float h = hist[cell * N_MU + i];
            #pragma unroll
            for (int k = 0; k < N_OUTK; ++k)
                acc[k] += h * s_lf[k + (N_MU - 1) - i];
        }
        #pragma unroll
        for (int k = 0; k < N_OUTK; ++k)
            out[cell * N_OUTK + k] = acc[k];
    }
}

// ---------------- launch ----------------------------------------------------

extern "C" void kernel_launch(void* const* d_in, const int* in_sizes, int n_in,
                              void* d_out, int out_size, void* d_ws, size_t ws_size,
                              hipStream_t stream) {
    const float4* lbm4 = (const float4*)d_in[0];   // [20e6, 3] f32
    const float4* m4   = (const float4*)d_in[1];   // [20e6]    f32
    const float*  lf   = (const float*)d_in[2];    // [51]      f32
    float* out = (float*)d_out;                    // [90,20,6] f32

    size_t ws_words = ws_size / 4;                 // u32/f32 units

    // ---- single-pass u16 sizing: slices | partial | spill | hist
    const long long PART1_WORDS = (long long)RP1 * (LDS_WORDS / 4) * 8; // 655360
    long long avail1 = (long long)ws_words - N_CELLS - 2 * SPILLW - PART1_WORDS;
    int C1 = avail1 > 0 ? (int)(avail1 / LDS_WORDS) : 0;
    if (C1 > C1_MAX) C1 = C1_MAX;

    if (C1 >= 128) {   // u16 carry margin argued for C >= 128
        unsigned* slices  = (unsigned*)d_ws;
        unsigned* partial = slices + (size_t)C1 * LDS_WORDS;
        unsigned* spill   = partial + PART1_WORDS;
        float*    hist    = (float*)(spill + 2 * SPILLW);
        int ppc = (N_PART + C1 - 1) / C1;
        hipMemsetAsync(spill, 0, 2 * SPILLW * sizeof(unsigned), stream);
        hist1_kernel<<<C1, HIST_BLOCK, 0, stream>>>(
            (const float*)d_in[0], (const float*)d_in[1], slices, spill, C1, ppc);
        int ta = RP1 * (LDS_WORDS / 4);
        reduce1a_kernel<<<(ta + 255) / 256, 256, 0, stream>>>(slices, partial, C1);
        int tb = N_CELLS16 / 4 + 2 * SPILLW;
        reduce1b_kernel<<<(tb + 255) / 256, 256, 0, stream>>>(partial, spill, hist);
        conv_kernel<<<(N_L * N_B + 255) / 256, 256, 0, stream>>>(hist, lf, out);
        return;
    }

    // ---- R=2 fallback (u32 fixed point)
    const long long PARTIAL_WORDS = (long long)RPARTS * 2 * VEC2 * 4;
    long long avail2 = (long long)ws_words - N_CELLS - 2 * SPILL_PER
                       - PARTIAL_WORDS;
    int C2 = avail2 > 0 ? (int)(avail2 / (2LL * LDS_CELLS)) : 0;
    if (C2 > C2_MAX) C2 = C2_MAX;
    C2 &= ~7;

    if (C2 >= 32) {
        unsigned* slices  = (unsigned*)d_ws;
        unsigned* partial = slices + (size_t)2 * C2 * LDS_CELLS;
        unsigned* spill   = partial + PARTIAL_WORDS;
        float*    hist    = (float*)(spill + 2 * SPILL_PER);
        int qpc = (QUADS + C2 - 1) / C2;
        hipMemsetAsync(spill, 0, 2 * SPILL_PER * sizeof(unsigned), stream);
        hist2_kernel<<<2 * C2, HIST_BLOCK, 0, stream>>>(lbm4, m4, slices, spill,
                                                        C2, qpc);
        int ta = RPARTS * 2 * VEC2;
        reduce2a_kernel<<<(ta + 255) / 256, 256, 0, stream>>>(slices, partial, C2);
        int tb = 2 * VEC2 + 2 * SPILL_PER;
        reduce2b_kernel<<<(tb + 255) / 256, 256, 0, stream>>>(partial, spill, hist);
        conv_kernel<<<(N_L * N_B + 255) / 256, 256, 0, stream>>>(hist, lf, out);
        return;
    }

    // ---- R=3 fallback (f32)
    long long avail3 = (long long)ws_words - N_CELLS;
    int C3 = avail3 > 0 ? (int)(avail3 / (3LL * SLICE3)) : 0;
    if (C3 > C3_MAX) C3 = C3_MAX;
    if (C3 >= 8) {
        float* slices = (float*)d_ws;
        float* hist   = slices + (size_t)3 * C3 * SLICE3;
        int qpc = (QUADS + C3 - 1) / C3;
        hist3_kernel<<<3 * C3, HIST_BLOCK, 0, stream>>>(lbm4, m4, slices, C3, qpc);
        reduce3_kernel<<<(N_CELLS + 255) / 256, 256, 0, stream>>>(slices, hist, C3);
        conv_kernel<<<(N_L * N_B + 255) / 256, 256, 0, stream>>>(hist, lf, out);
        return;
    }

    // ---- tiny-ws fallback: global atomics
    float* hist = (float*)d_ws;
    zero_hist_kernel<<<(N_CELLS + 255) / 256, 256, 0, stream>>>(hist);
    hist_atomic_kernel<<<(QUADS + 255) / 256, 256, 0, stream>>>(lbm4, m4, hist);
    conv_kernel<<<(N_L * N_B + 255) / 256, 256, 0, stream>>>(hist, lf, out);
}